// Round 5
// baseline (91.206 us; speedup 1.0000x reference)
//
#include <hip/hip_runtime.h>
#include <hip/hip_bf16.h>

#define N_TOK 65536
#define KCB   512
#define DIM   64
#define KSLICES 4   // waves per block, each covers KCB/KSLICES codebook rows

typedef __attribute__((ext_vector_type(4))) float f32x4;

// Tiny one-shot kernel: csq[k] = sum(cb[k]^2) into workspace.
__global__ __launch_bounds__(256) void vq_csq_kernel(
    const float* __restrict__ cb, float* __restrict__ csq) {
  const int k = blockIdx.x * 256 + threadIdx.x;
  if (k >= KCB) return;
  const float4* row4 = reinterpret_cast<const float4*>(cb + (size_t)k * DIM);
  float s = 0.f;
#pragma unroll
  for (int i = 0; i < DIM / 4; ++i) {
    float4 c = row4[i];
    s = fmaf(c.x, c.x, s);
    s = fmaf(c.y, c.y, s);
    s = fmaf(c.z, c.z, s);
    s = fmaf(c.w, c.w, s);
  }
  csq[k] = s;
}

// Block = 256 threads = 4 waves; 64 tokens (one per lane).
// Wave w scores rows [w*128, w*128+128) for its lane's token; LDS merge.
// Token held in VGPRs via OPAQUE asm loads (compiler cannot rematerialize
// them into the k-loop — the round-2/3 failure, VGPR=52 + in-loop refetch).
// Codebook reads are wave-uniform -> scalar/broadcast path, no LDS at all
// in the inner loop (round-4 failure: LDS-BW-bound at 1.33 flop/byte).
__global__ __launch_bounds__(256, 4) void vq_argmin_kernel(
    const float* __restrict__ cb,
    const float* __restrict__ emb,
    const float* __restrict__ csqg,
    float* __restrict__ out) {
  __shared__ float rbest[KSLICES][64];
  __shared__ int   ridx[KSLICES][64];

  const int tid  = threadIdx.x;
  const int lane = tid & 63;
  const int wave = tid >> 6;
  const int t    = blockIdx.x * 64 + lane;

  // ---- opaque register-resident token load: 16 x global_load_dwordx4 ----
  f32x4 ev[DIM / 4];
  const float* ep = emb + (size_t)t * DIM;
#pragma unroll
  for (int i = 0; i < DIM / 4; ++i) {
    asm volatile("global_load_dwordx4 %0, %1, off offset:%2"
                 : "=v"(ev[i])
                 : "v"(ep), "i"(16 * i));
  }
  asm volatile("s_waitcnt vmcnt(0)" ::: "memory");
  __builtin_amdgcn_sched_barrier(0);  // rule 18: no hoisting above the wait

  // Wave-uniform slice base -> scalar-path codebook loads.
  const int kbase = __builtin_amdgcn_readfirstlane(wave * (KCB / KSLICES));

  float best = 3.4e38f;
  int bidx = kbase;

#pragma unroll 2
  for (int kk = 0; kk < KCB / KSLICES; ++kk) {
    const int k = kbase + kk;
    const f32x4* row4 = reinterpret_cast<const f32x4*>(cb + (size_t)k * DIM);
    float s0 = 0.f, s1 = 0.f, s2 = 0.f, s3 = 0.f;
#pragma unroll
    for (int i = 0; i < DIM / 4; ++i) {
      const f32x4 c = row4[i];  // uniform address, reused by all 64 lanes
      s0 = fmaf(c[0], ev[i][0], s0);
      s1 = fmaf(c[1], ev[i][1], s1);
      s2 = fmaf(c[2], ev[i][2], s2);
      s3 = fmaf(c[3], ev[i][3], s3);
    }
    const float dot = (s0 + s1) + (s2 + s3);
    const float score = fmaf(-2.f, dot, csqg[k]);
    if (score < best) {   // strict < keeps lowest index within slice
      best = score;
      bidx = k;
    }
  }

  rbest[wave][lane] = best;
  ridx[wave][lane] = bidx;
  __syncthreads();

  if (tid < 64) {  // ascending-slice merge preserves lowest-index ties
    float b = rbest[0][lane];
    int bi = ridx[0][lane];
#pragma unroll
    for (int w = 1; w < KSLICES; ++w) {
      const float ob = rbest[w][lane];
      const int oi = ridx[w][lane];
      if (ob < b) { b = ob; bi = oi; }
    }
    out[(size_t)2 * N_TOK * DIM + blockIdx.x * 64 + lane] = (float)bi;
  }
}

// Gather-write of the two quantized sections. 16 lanes per token, one float4
// each; fully coalesced stores; codebook (128 KB) is L2-resident.
__global__ __launch_bounds__(256) void vq_gather_kernel(
    const float* __restrict__ cb,
    float* __restrict__ out) {
  const int gid = blockIdx.x * 256 + threadIdx.x;  // 0 .. N_TOK*16-1
  const int t = gid >> 4;
  const int j = gid & 15;

  const int idx = (int)out[(size_t)2 * N_TOK * DIM + t];

  const float4* cb4 = reinterpret_cast<const float4*>(cb);
  float4* out4 = reinterpret_cast<float4*>(out);

  const float4 v = cb4[idx * (DIM / 4) + j];
  out4[(size_t)t * (DIM / 4) + j] = v;                               // quantized_codebook
  out4[(size_t)N_TOK * (DIM / 4) + (size_t)t * (DIM / 4) + j] = v;   // straight_through
}

extern "C" void kernel_launch(void* const* d_in, const int* in_sizes, int n_in,
                              void* d_out, int out_size, void* d_ws, size_t ws_size,
                              hipStream_t stream) {
  const float* cb  = (const float*)d_in[0];   // (512, 64) f32
  const float* emb = (const float*)d_in[1];   // (65536, 1, 64) f32
  float* out = (float*)d_out;                 // [2*N*D quantized | N index] f32
  float* csq = (float*)d_ws;                  // 512 floats scratch

  vq_csq_kernel<<<KCB / 256, 256, 0, stream>>>(cb, csq);
  vq_argmin_kernel<<<N_TOK / 64, 256, 0, stream>>>(cb, emb, csq, out);
  vq_gather_kernel<<<(N_TOK * 16) / 256, 256, 0, stream>>>(cb, out);
}